// Round 6
// baseline (335.358 us; speedup 1.0000x reference)
//
#include <hip/hip_runtime.h>

#define B_ 8
#define T_ 32
#define N_ 500
#define DP 200
#define DC 128
#define H_ 4
#define U_ 64
#define NP 512           // padded N
#define COLS (T_ * U_)   // 2048
#define K4 (H_ * NP)     // 2048 fused K

typedef __attribute__((ext_vector_type(8))) short bf16x8;
typedef __attribute__((ext_vector_type(4))) float f32x4;

typedef const __attribute__((address_space(1))) void* gcptr_t;
typedef __attribute__((address_space(3))) void* lptr_t;

// async 16B/lane global->LDS; lds base must be wave-uniform (dest = base + lane*16)
__device__ __forceinline__ void async16(const void* g, void* lds) {
    __builtin_amdgcn_global_load_lds((gcptr_t)g, (lptr_t)lds, 16, 0, 0);
}

__device__ __forceinline__ ushort f2bf(float f) {
    unsigned u = __float_as_uint(f);
    unsigned r = (u + 0x7FFFu + ((u >> 16) & 1u)) >> 16;  // RTNE
    return (ushort)r;
}

// ---------------------------------------------------------------------------
// WT[h][u][d] = bf16(0.25 * Wmsg[h][d][u])  (0.25 = head mean, exact pow2)
__global__ void prep_wT(const float* __restrict__ Wmsg, ushort* __restrict__ WT) {
    int idx = blockIdx.x * 256 + threadIdx.x;
    int h = idx >> 13, u = (idx >> 7) & 63, d = idx & 127;
    WT[idx] = f2bf(0.25f * Wmsg[((size_t)h * DC + d) * U_ + u]);
}

// ---------------------------------------------------------------------------
// Projections for ALL heads, 4 node-rows per block. hsrc/hdst [B,H,N,U] fp32.
__global__ void __launch_bounds__(512) proj_all(
    const float* __restrict__ prev, const float* __restrict__ Wsrc,
    const float* __restrict__ Wdst, float* __restrict__ hsrc,
    float* __restrict__ hdst)
{
    __shared__ float rows[4 * DP];
    const int tid = threadIdx.x;
    const int bn0 = blockIdx.x * 4;
    for (int e = tid; e < 4 * DP; e += 512) rows[e] = prev[(size_t)bn0 * DP + e];
    __syncthreads();
    const int u = tid & 63;
    const int h = (tid >> 6) & 3;
    const int isdst = tid >> 8;
    const float* W = (isdst ? Wdst : Wsrc) + (size_t)h * DP * U_;
    float a0 = 0.f, a1 = 0.f, a2 = 0.f, a3 = 0.f;
#pragma unroll 4
    for (int d = 0; d < DP; ++d) {
        float w = W[d * U_ + u];
        a0 = fmaf(rows[d], w, a0);
        a1 = fmaf(rows[DP + d], w, a1);
        a2 = fmaf(rows[2 * DP + d], w, a2);
        a3 = fmaf(rows[3 * DP + d], w, a3);
    }
    float acc[4] = {a0, a1, a2, a3};
    float* o = isdst ? hdst : hsrc;
#pragma unroll
    for (int r = 0; r < 4; ++r) {
        int bn = bn0 + r, b = bn / N_, n = bn - b * N_;
        o[(((size_t)b * H_ + h) * N_ + n) * U_ + u] = acc[r];
    }
}

// ---------------------------------------------------------------------------
// Scores + softmax. lrelu(x)=0.6x+0.4|x|; row-constant 0.6*P_i cancels.
// 256 threads, 2 j per thread (halves waves + LDS/shuffle overhead vs R5),
// 128 i-blocks -> writes the full padded 512x512 tile (pad j cols get exact
// 0; pad i rows get garbage consumed only by masked-out output rows), so
// zero_fill is eliminated. Outer loop stays `#pragma unroll 1` (R5 lesson:
// full unroll -> 128 VGPR + scratch spill).
__global__ void __launch_bounds__(256) attn_softmax5(
    const float* __restrict__ hsrc, const float* __restrict__ hdst,
    const float* __restrict__ a_all, ushort* __restrict__ attnB)
{
    const int i0 = blockIdx.x * 4, b = blockIdx.y, h = blockIdx.z;
    const int tid = threadIdx.x;
    __shared__ float s_src[4][U_];
    __shared__ float s_a[U_];
    __shared__ float red[16];     // [wave][i]
    __shared__ float s_mx[4], s_rs[4];

    {
        int r = tid >> 6, c = tid & 63;
        int gi = i0 + r;
        s_src[r][c] = (gi < N_) ?
            hsrc[(((size_t)b * H_ + h) * N_ + gi) * U_ + c] : 0.f;
        if (tid < 64) s_a[tid] = a_all[h * U_ + tid];
    }
    __syncthreads();

    const int j0 = tid, j1 = tid + 256;
    const bool v1 = j1 < N_;            // j0 < 256 always valid
    const float4* dp0 = (const float4*)&hdst[(((size_t)b * H_ + h) * N_ + j0) * U_];
    const float4* dp1 = (const float4*)&hdst[(((size_t)b * H_ + h) * N_ + (v1 ? j1 : 0)) * U_];

    float q0 = 0.f, q1 = 0.f;
    float av0[4] = {}, av1[4] = {};
#pragma unroll 1
    for (int kc = 0; kc < 4; ++kc) {    // SEQUENTIAL: 4 chunks of 16
        float4 a[4], d0[4], d1[4];
#pragma unroll
        for (int k = 0; k < 4; ++k) {
            a[k]  = *(const float4*)&s_a[kc * 16 + 4 * k];
            d0[k] = dp0[kc * 4 + k];
            d1[k] = dp1[kc * 4 + k];
        }
#pragma unroll
        for (int k = 0; k < 4; ++k) {
            q0 = fmaf(d0[k].x, a[k].x, q0); q0 = fmaf(d0[k].y, a[k].y, q0);
            q0 = fmaf(d0[k].z, a[k].z, q0); q0 = fmaf(d0[k].w, a[k].w, q0);
            q1 = fmaf(d1[k].x, a[k].x, q1); q1 = fmaf(d1[k].y, a[k].y, q1);
            q1 = fmaf(d1[k].z, a[k].z, q1); q1 = fmaf(d1[k].w, a[k].w, q1);
        }
#pragma unroll
        for (int i = 0; i < 4; ++i) {
            float x;
#pragma unroll
            for (int k = 0; k < 4; ++k) {
                const float4 sv = *(const float4*)&s_src[i][kc * 16 + 4 * k];
                x = sv.x + d0[k].x; av0[i] = fmaf(fabsf(x), a[k].x, av0[i]);
                x = sv.y + d0[k].y; av0[i] = fmaf(fabsf(x), a[k].y, av0[i]);
                x = sv.z + d0[k].z; av0[i] = fmaf(fabsf(x), a[k].z, av0[i]);
                x = sv.w + d0[k].w; av0[i] = fmaf(fabsf(x), a[k].w, av0[i]);
                x = sv.x + d1[k].x; av1[i] = fmaf(fabsf(x), a[k].x, av1[i]);
                x = sv.y + d1[k].y; av1[i] = fmaf(fabsf(x), a[k].y, av1[i]);
                x = sv.z + d1[k].z; av1[i] = fmaf(fabsf(x), a[k].z, av1[i]);
                x = sv.w + d1[k].w; av1[i] = fmaf(fabsf(x), a[k].w, av1[i]);
            }
        }
    }
    const float q06 = 0.6f * q0, q16 = 0.6f * q1;
    float sc0[4], sc1[4];
#pragma unroll
    for (int i = 0; i < 4; ++i) {
        sc0[i] = fmaf(0.4f, av0[i], q06);
        sc1[i] = v1 ? fmaf(0.4f, av1[i], q16) : -1e30f;
    }

    const int wave = tid >> 6, lane = tid & 63;
#pragma unroll
    for (int i = 0; i < 4; ++i) {
        float m = fmaxf(sc0[i], sc1[i]);
        for (int off = 1; off < 64; off <<= 1) m = fmaxf(m, __shfl_xor(m, off));
        if (lane == 0) red[wave * 4 + i] = m;
    }
    __syncthreads();
    if (tid < 4) {
        float mm = red[tid];
        for (int w = 1; w < 4; ++w) mm = fmaxf(mm, red[w * 4 + tid]);
        s_mx[tid] = mm;
    }
    __syncthreads();
    float e0[4], e1[4];
#pragma unroll
    for (int i = 0; i < 4; ++i) {
        e0[i] = __expf(sc0[i] - s_mx[i]);
        e1[i] = __expf(sc1[i] - s_mx[i]);   // -1e30 -> 0
        float s = e0[i] + e1[i];
        for (int off = 1; off < 64; off <<= 1) s += __shfl_xor(s, off);
        if (lane == 0) red[wave * 4 + i] = s;
    }
    __syncthreads();
    if (tid < 4) {
        float ss = 0.f;
        for (int w = 0; w < 4; ++w) ss += red[w * 4 + tid];
        s_rs[tid] = 1.0f / ss;
    }
    __syncthreads();
#pragma unroll
    for (int i = 0; i < 4; ++i) {
        ushort* rowp = &attnB[(((size_t)b * H_ + h) * NP + i0 + i) * NP];
        rowp[j0] = f2bf(e0[i] * s_rs[i]);
        rowp[j1] = f2bf(e1[i] * s_rs[i]);   // pad j: exact 0
    }
}

// ---------------------------------------------------------------------------
// FUSED msg: curr tile staged once, 4 heads looped over LDS-resident W.
// msgT[b][h][col=t*64+u][m] = bf16(0.25 * sum_d curr[b,t,m,d]*Wmsg_h[d,u])
__global__ void __launch_bounds__(256) msg_all(
    const float* __restrict__ curr, const ushort* __restrict__ WT,
    ushort* __restrict__ msgT)
{
    __shared__ ushort As[128 * 136];  // [m][d] pad+8
    __shared__ ushort Bs[64 * 136];   // [u][d] pad+8
    const int tid = threadIdx.x;
    const int m0 = blockIdx.x * 128, t = blockIdx.y, b = blockIdx.z;

    const float* cbase = curr + (size_t)(b * T_ + t) * N_ * DC;
#pragma unroll
    for (int it = 0; it < 16; ++it) {
        int e = it * 1024 + tid * 4;
        int r = e >> 7, c = e & 127;
        int gm = m0 + r;
        float4 v; v.x = v.y = v.z = v.w = 0.f;
        if (gm < N_) v = *(const float4*)&cbase[(size_t)gm * DC + c];
        ushort4 o;
        o.x = f2bf(v.x); o.y = f2bf(v.y); o.z = f2bf(v.z); o.w = f2bf(v.w);
        *(ushort4*)&As[r * 136 + c] = o;
    }

    const int wave = tid >> 6, lane = tid & 63;
    const int r15 = lane & 15, quad = lane >> 4;
    const int wm = wave >> 1, wu = wave & 1;

    for (int h = 0; h < H_; ++h) {
        __syncthreads();  // prior-iter Bs reads done (1st iter: As staged)
#pragma unroll
        for (int it = 0; it < 4; ++it) {
            int e = it * 2048 + tid * 8;
            int u = e >> 7, d = e & 127;
            *(uint4*)&Bs[u * 136 + d] =
                *(const uint4*)&WT[(size_t)h * 8192 + u * 128 + d];
        }
        __syncthreads();

        f32x4 acc[4][2] = {};
#pragma unroll
        for (int ks = 0; ks < 4; ++ks) {
            bf16x8 af[4], bg[2];
#pragma unroll
            for (int f = 0; f < 4; ++f)
                af[f] = *(const bf16x8*)&As[(wm * 64 + f * 16 + r15) * 136 + ks * 32 + quad * 8];
#pragma unroll
            for (int g = 0; g < 2; ++g)
                bg[g] = *(const bf16x8*)&Bs[(wu * 32 + g * 16 + r15) * 136 + ks * 32 + quad * 8];
#pragma unroll
            for (int f = 0; f < 4; ++f)
#pragma unroll
                for (int g = 0; g < 2; ++g)
                    acc[f][g] = __builtin_amdgcn_mfma_f32_16x16x32_bf16(af[f], bg[g], acc[f][g], 0, 0, 0);
        }
#pragma unroll
        for (int f = 0; f < 4; ++f)
#pragma unroll
            for (int g = 0; g < 2; ++g) {
                int m = m0 + wm * 64 + f * 16 + quad * 4;
                int u = wu * 32 + g * 16 + r15;
                int col = t * U_ + u;
                ushort4 o;
                o.x = f2bf(acc[f][g][0]); o.y = f2bf(acc[f][g][1]);
                o.z = f2bf(acc[f][g][2]); o.w = f2bf(acc[f][g][3]);
                *(ushort4*)&msgT[(((size_t)b * H_ + h) * COLS + col) * NP + m] = o;
            }
    }
}

// ---------------------------------------------------------------------------
// FUSED single GEMM per b: C[col=2048][i=512], K=2048 segmented over 4 heads.
// R6: global_load_lds (16B/lane, direct-to-LDS) + XOR column swizzle
// (chunk ^= row&7) instead of +8 pad -- async dest must be lane-contiguous;
// swizzle spreads b128 frag reads across all 32 banks (2 lanes/bank = free).
__global__ void __launch_bounds__(256) gemm_big2(
    const ushort* __restrict__ msgT, const ushort* __restrict__ attnB,
    float* __restrict__ out)
{
    __shared__ ushort As[128 * 64];   // [row][chunk-swizzled 64 cols]
    __shared__ ushort Bs[128 * 64];
    const int tid = threadIdx.x;
    const int mt = blockIdx.x, nt = blockIdx.y, b = blockIdx.z;

    const int wave = tid >> 6, lane = tid & 63;
    const int r15 = lane & 15, quad = lane >> 4;
    const int wm = wave >> 1, wn = wave & 1;
    const int lrow = lane >> 3, lch = lane & 7;

    f32x4 acc[4][4] = {};
    for (int kk = 0; kk < K4; kk += 64) {
        const int hh = kk >> 9, ko = kk & (NP - 1);
        const ushort* Ab = msgT + (((size_t)b * H_ + hh) * COLS + mt * 128) * NP + ko;
        const ushort* Bb = attnB + (((size_t)b * H_ + hh) * NP + nt * 128) * NP + ko;
        // wave w stages rows [w*32, w*32+32) of both tiles: 4 loads x 8 rows
#pragma unroll
        for (int l = 0; l < 4; ++l) {
            const int R0 = wave * 32 + l * 8;          // wave-uniform
            const int row = R0 + lrow;
            const int gch = lch ^ (row & 7);
            async16(Ab + (size_t)row * NP + gch * 8, &As[R0 * 64]);
            async16(Bb + (size_t)row * NP + gch * 8, &Bs[R0 * 64]);
        }
        __syncthreads();   // compiler drains vmcnt before s_barrier
#pragma unroll
        for (int ks = 0; ks < 2; ++ks) {
            bf16x8 af[4], bg[4];
#pragma unroll
            for (int f = 0; f < 4; ++f) {
                int row = wm * 64 + f * 16 + r15;
                int c = (ks * 4 + quad) ^ (row & 7);
                af[f] = *(const bf16x8*)&As[row * 64 + c * 8];
            }
#pragma unroll
            for (int g = 0; g < 4; ++g) {
                int row = wn * 64 + g * 16 + r15;
                int c = (ks * 4 + quad) ^ (row & 7);
                bg[g] = *(const bf16x8*)&Bs[row * 64 + c * 8];
            }
#pragma unroll
            for (int f = 0; f < 4; ++f)
#pragma unroll
                for (int g = 0; g < 4; ++g)
                    acc[f][g] = __builtin_amdgcn_mfma_f32_16x16x32_bf16(af[f], bg[g], acc[f][g], 0, 0, 0);
        }
        __syncthreads();
    }

    const int t = mt * 2 + wm;
#pragma unroll
    for (int f = 0; f < 4; ++f)
#pragma unroll
        for (int g = 0; g < 4; ++g) {
            int u = f * 16 + quad * 4;
            int i = nt * 128 + wn * 64 + g * 16 + r15;
            if (i < N_) {
                float4 v;
                v.x = acc[f][g][0]; v.y = acc[f][g][1];
                v.z = acc[f][g][2]; v.w = acc[f][g][3];
                *(float4*)&out[(((size_t)b * T_ + t) * N_ + i) * U_ + u] = v;
            }
        }
}

// ---------------------------------------------------------------------------
// FALLBACK (small ws): per-head msg + gemm, same layouts.
__global__ void __launch_bounds__(256) msg_mfma(
    const float* __restrict__ curr, const ushort* __restrict__ WTh,
    ushort* __restrict__ msgT)
{
    __shared__ ushort As[128 * 136];
    __shared__ ushort Bs[64 * 136];
    const int tid = threadIdx.x;
    const int m0 = blockIdx.x * 128, t = blockIdx.y, b = blockIdx.z;

    const float* cbase = curr + (size_t)(b * T_ + t) * N_ * DC;
#pragma unroll
    for (int it = 0; it < 16; ++it) {
        int e = it * 1024 + tid * 4;
        int r = e >> 7, c = e & 127;
        int gm = m0 + r;
        float4 v; v.x = v.y = v.z = v.w = 0.f;
        if (gm < N_) v = *(const float4*)&cbase[(size_t)gm * DC + c];
        ushort4 o;
        o.x = f2bf(v.x); o.y = f2bf(v.y); o.z = f2bf(v.z); o.w = f2bf(v.w);
        *(ushort4*)&As[r * 136 + c] = o;
    }
#pragma unroll
    for (int it = 0; it < 4; ++it) {
        int e = it * 2048 + tid * 8;
        int u = e >> 7, d = e & 127;
        *(uint4*)&Bs[u * 136 + d] = *(const uint4*)&WTh[u * 128 + d];
    }
    __syncthreads();

    const int wave = tid >> 6, lane = tid & 63;
    const int r15 = lane & 15, quad = lane >> 4;
    const int wm = wave >> 1, wu = wave & 1;

    f32x4 acc[4][2] = {};
#pragma unroll
    for (int ks = 0; ks < 4; ++ks) {
        bf16x8 af[4], bg[2];
#pragma unroll
        for (int f = 0; f < 4; ++f)
            af[f] = *(const bf16x8*)&As[(wm * 64 + f * 16 + r15) * 136 + ks * 32 + quad * 8];
#pragma unroll
        for (int g = 0; g < 2; ++g)
            bg[g] = *(const bf16x8*)&Bs[(wu * 32 + g * 16 + r15) * 136 + ks * 32 + quad * 8];
#pragma unroll
        for (int f = 0; f < 4; ++f)
#pragma unroll
            for (int g = 0; g < 2; ++g)
                acc[f][g] = __builtin_amdgcn_mfma_f32_16x16x32_bf16(af[f], bg[g], acc[f][g], 0, 0, 0);
    }
#pragma unroll
    for (int f = 0; f < 4; ++f)
#pragma unroll
        for (int g = 0; g < 2; ++g) {
            int m = m0 + wm * 64 + f * 16 + quad * 4;
            int u = wu * 32 + g * 16 + r15;
            int col = t * U_ + u;
            ushort4 o;
            o.x = f2bf(acc[f][g][0]); o.y = f2bf(acc[f][g][1]);
            o.z = f2bf(acc[f][g][2]); o.w = f2bf(acc[f][g][3]);
            *(ushort4*)&msgT[((size_t)b * COLS + col) * NP + m] = o;
        }
}

__global__ void __launch_bounds__(256) gemm_mfma(
    const ushort* __restrict__ msgT, const ushort* __restrict__ attnB,
    float* __restrict__ out, int h, int init)
{
    __shared__ ushort As[64 * 72];
    __shared__ ushort Bs[64 * 72];
    const int tid = threadIdx.x;
    const int ct = blockIdx.x, it = blockIdx.y, b = blockIdx.z;

    const ushort* Ab = msgT + ((size_t)b * COLS + ct * 64) * NP;
    const ushort* Bb = attnB + (((size_t)b * H_ + h) * NP + it * 64) * NP;

    const int wave = tid >> 6, lane = tid & 63;
    const int r15 = lane & 15, quad = lane >> 4;
    const int wm = wave >> 1, wn = wave & 1;
    const int srow = tid >> 3, scol = (tid & 7) * 8;

    f32x4 acc[2][2] = {};
    for (int kk = 0; kk < NP; kk += 64) {
#pragma unroll
        for (int it2 = 0; it2 < 2; ++it2) {
            int rr = it2 * 32 + srow;
            *(uint4*)&As[rr * 72 + scol] = *(const uint4*)&Ab[(size_t)rr * NP + kk + scol];
            *(uint4*)&Bs[rr * 72 + scol] = *(const uint4*)&Bb[(size_t)rr * NP + kk + scol];
        }
        __syncthreads();
#pragma unroll
        for (int ks = 0; ks < 2; ++ks) {
            bf16x8 af[2], bg[2];
#pragma unroll
            for (int f = 0; f < 2; ++f)
                af[f] = *(const bf16x8*)&As[(wm * 32 + f * 16 + r15) * 72 + ks * 32 + quad * 8];
#pragma unroll
            for (int g = 0; g < 2; ++g)
                bg[g] = *(const bf16x8*)&Bs[(wn * 32 + g * 16 + r15) * 72 + ks * 32 + quad * 8];
#pragma unroll
            for (int f = 0; f < 2; ++f)
#pragma unroll
                for (int g = 0; g < 2; ++g)
                    acc[f][g] = __builtin_amdgcn_mfma_f32_16x16x32_bf16(af[f], bg[g], acc[f][g], 0, 0, 0);
        }
        __syncthreads();
    }

    const int t = ct;
#pragma unroll
    for (int f = 0; f < 2; ++f)
#pragma unroll
        for (int g = 0; g < 2; ++g) {
            int u = wm * 32 + f * 16 + quad * 4;
            int i = it * 64 + wn * 32 + g * 16 + r15;
            if (i < N_) {
                float* op = out + (((size_t)b * T_ + t) * N_ + i) * U_ + u;
                float4 v;
                v.x = acc[f][g][0]; v.y = acc[f][g][1];
                v.z = acc[f][g][2]; v.w = acc[f][g][3];
                if (!init) {
                    float4 old = *(const float4*)op;
                    v.x += old.x; v.y += old.y; v.z += old.z; v.w += old.w;
                }
                *(float4*)op = v;
            }
        }
}

// ---------------------------------------------------------------------------
extern "C" void kernel_launch(void* const* d_in, const int* in_sizes, int n_in,
                              void* d_out, int out_size, void* d_ws, size_t ws_size,
                              hipStream_t stream)
{
    const float* prev = (const float*)d_in[0];
    const float* curr = (const float*)d_in[1];
    const float* Wsrc = (const float*)d_in[2];
    const float* Wdst = (const float*)d_in[3];
    const float* avec = (const float*)d_in[4];
    const float* Wmsg = (const float*)d_in[5];
    float* out = (float*)d_out;

    const size_t attnB_b = (size_t)B_ * H_ * NP * NP * 2;   // 16.78 MB
    const size_t msgT4_b = (size_t)B_ * H_ * COLS * NP * 2; // 67.1 MB
    const size_t msgT1_b = (size_t)B_ * COLS * NP * 2;      // 16.78 MB
    const size_t WT_b    = (size_t)H_ * U_ * DC * 2;
    const size_t hx_b    = (size_t)B_ * H_ * N_ * U_ * 4;   // 4.1 MB

    const bool fused = ws_size >= attnB_b + msgT4_b + WT_b + 2 * hx_b;
    const size_t msg_b = fused ? msgT4_b : msgT1_b;

    ushort* attnB = (ushort*)d_ws;
    ushort* msgT  = (ushort*)((char*)d_ws + attnB_b);
    ushort* WT    = (ushort*)((char*)d_ws + attnB_b + msg_b);
    float*  hsrc  = (float*)((char*)WT + WT_b);
    float*  hdst  = (float*)((char*)hsrc + hx_b);

    prep_wT<<<128, 256, 0, stream>>>(Wmsg, WT);
    proj_all<<<1000, 512, 0, stream>>>(prev, Wsrc, Wdst, hsrc, hdst);
    // 128 i-blocks: writes all 512 rows (+ pad j cols) -> no zero_fill needed
    attn_softmax5<<<dim3(128, B_, H_), 256, 0, stream>>>(hsrc, hdst, avec, attnB);

    if (fused) {
        msg_all<<<dim3(4, T_, B_), 256, 0, stream>>>(curr, WT, msgT);
        gemm_big2<<<dim3(16, 4, B_), 256, 0, stream>>>(msgT, attnB, out);
    } else {
        for (int h = 0; h < H_; ++h) {
            msg_mfma<<<dim3(4, T_, B_), 256, 0, stream>>>(
                curr, WT + (size_t)h * U_ * DC, msgT);
            gemm_mfma<<<dim3(32, 8, B_), 256, 0, stream>>>(
                msgT, attnB, out, h, h == 0 ? 1 : 0);
        }
    }
}

// Round 7
// 297.732 us; speedup vs baseline: 1.1264x; 1.1264x over previous
//
#include <hip/hip_runtime.h>

#define B_ 8
#define T_ 32
#define N_ 500
#define DP 200
#define DC 128
#define H_ 4
#define U_ 64
#define NP 512           // padded N
#define COLS (T_ * U_)   // 2048
#define K4 (H_ * NP)     // 2048 fused K

typedef __attribute__((ext_vector_type(8))) short bf16x8;
typedef __attribute__((ext_vector_type(4))) float f32x4;

typedef const __attribute__((address_space(1))) void* gcptr_t;
typedef __attribute__((address_space(3))) void* lptr_t;

// async 16B/lane global->LDS; lds base must be wave-uniform (dest = base + lane*16)
__device__ __forceinline__ void async16(const void* g, void* lds) {
    __builtin_amdgcn_global_load_lds((gcptr_t)g, (lptr_t)lds, 16, 0, 0);
}

__device__ __forceinline__ ushort f2bf(float f) {
    unsigned u = __float_as_uint(f);
    unsigned r = (u + 0x7FFFu + ((u >> 16) & 1u)) >> 16;  // RTNE
    return (ushort)r;
}

// ---------------------------------------------------------------------------
// WT[h][u][d] = bf16(0.25 * Wmsg[h][d][u])  (0.25 = head mean, exact pow2)
__global__ void prep_wT(const float* __restrict__ Wmsg, ushort* __restrict__ WT) {
    int idx = blockIdx.x * 256 + threadIdx.x;
    int h = idx >> 13, u = (idx >> 7) & 63, d = idx & 127;
    WT[idx] = f2bf(0.25f * Wmsg[((size_t)h * DC + d) * U_ + u]);
}

// ---------------------------------------------------------------------------
// Projections for ALL heads, 4 node-rows per block. hsrc/hdst [B,H,N,U] fp32.
__global__ void __launch_bounds__(512) proj_all(
    const float* __restrict__ prev, const float* __restrict__ Wsrc,
    const float* __restrict__ Wdst, float* __restrict__ hsrc,
    float* __restrict__ hdst)
{
    __shared__ float rows[4 * DP];
    const int tid = threadIdx.x;
    const int bn0 = blockIdx.x * 4;
    for (int e = tid; e < 4 * DP; e += 512) rows[e] = prev[(size_t)bn0 * DP + e];
    __syncthreads();
    const int u = tid & 63;
    const int h = (tid >> 6) & 3;
    const int isdst = tid >> 8;
    const float* W = (isdst ? Wdst : Wsrc) + (size_t)h * DP * U_;
    float a0 = 0.f, a1 = 0.f, a2 = 0.f, a3 = 0.f;
#pragma unroll 4
    for (int d = 0; d < DP; ++d) {
        float w = W[d * U_ + u];
        a0 = fmaf(rows[d], w, a0);
        a1 = fmaf(rows[DP + d], w, a1);
        a2 = fmaf(rows[2 * DP + d], w, a2);
        a3 = fmaf(rows[3 * DP + d], w, a3);
    }
    float acc[4] = {a0, a1, a2, a3};
    float* o = isdst ? hdst : hsrc;
#pragma unroll
    for (int r = 0; r < 4; ++r) {
        int bn = bn0 + r, b = bn / N_, n = bn - b * N_;
        o[(((size_t)b * H_ + h) * N_ + n) * U_ + u] = acc[r];
    }
}

// ---------------------------------------------------------------------------
// Scores + softmax (R5-proven shape: 512 thr, 1 j/thread, VGPR 36).
// lrelu(x)=0.6x+0.4|x|; row-constant 0.6*P_i cancels in softmax ->
// score' = 0.6*Q_j + 0.4*sum_u a_u*|s_iu+d_ju|.
// Outer chunk loop `#pragma unroll 1` (R5 lesson: full unroll -> 128 VGPR +
// scratch spill). Grid 128 i-blocks + unconditional store covers the full
// padded 512x512 tile (pad j cols exact 0; pad i rows finite garbage read
// only by masked output rows) -> no zero_fill pass needed.
__global__ void __launch_bounds__(512) attn_softmax6(
    const float* __restrict__ hsrc, const float* __restrict__ hdst,
    const float* __restrict__ a_all, ushort* __restrict__ attnB)
{
    const int i0 = blockIdx.x * 4, b = blockIdx.y, h = blockIdx.z;
    const int tid = threadIdx.x;
    __shared__ float s_src[4][U_];
    __shared__ float s_a[U_];
    __shared__ float red[32];     // [wave][i]
    __shared__ float s_mx[4], s_rs[4];

    if (tid < 256) {
        int gi = i0 + (tid >> 6);
        s_src[tid >> 6][tid & 63] = (gi < N_) ?
            hsrc[(((size_t)b * H_ + h) * N_ + gi) * U_ + (tid & 63)] : 0.f;
    } else if (tid < 320)
        s_a[tid - 256] = a_all[h * U_ + (tid - 256)];
    __syncthreads();

    const int j = tid;
    const bool valid = j < N_;
    const float4* dp =
        (const float4*)&hdst[(((size_t)b * H_ + h) * N_ + (valid ? j : 0)) * U_];

    float av0 = 0.f, av1 = 0.f, av2 = 0.f, av3 = 0.f;
    float q = 0.f;
#pragma unroll 1
    for (int kc = 0; kc < 4; ++kc) {         // SEQUENTIAL: 4 chunks of 16
        float4 d0 = dp[kc * 4 + 0];
        float4 d1 = dp[kc * 4 + 1];
        float4 d2 = dp[kc * 4 + 2];
        float4 d3 = dp[kc * 4 + 3];
        float4 a0 = *(const float4*)&s_a[kc * 16 + 0];
        float4 a1 = *(const float4*)&s_a[kc * 16 + 4];
        float4 a2 = *(const float4*)&s_a[kc * 16 + 8];
        float4 a3 = *(const float4*)&s_a[kc * 16 + 12];

        q = fmaf(d0.x, a0.x, q); q = fmaf(d0.y, a0.y, q);
        q = fmaf(d0.z, a0.z, q); q = fmaf(d0.w, a0.w, q);
        q = fmaf(d1.x, a1.x, q); q = fmaf(d1.y, a1.y, q);
        q = fmaf(d1.z, a1.z, q); q = fmaf(d1.w, a1.w, q);
        q = fmaf(d2.x, a2.x, q); q = fmaf(d2.y, a2.y, q);
        q = fmaf(d2.z, a2.z, q); q = fmaf(d2.w, a2.w, q);
        q = fmaf(d3.x, a3.x, q); q = fmaf(d3.y, a3.y, q);
        q = fmaf(d3.z, a3.z, q); q = fmaf(d3.w, a3.w, q);

#pragma unroll
        for (int i = 0; i < 4; ++i) {
            float acc = (i == 0) ? av0 : (i == 1) ? av1 : (i == 2) ? av2 : av3;
            float4 s0 = *(const float4*)&s_src[i][kc * 16 + 0];
            float4 s1 = *(const float4*)&s_src[i][kc * 16 + 4];
            float4 s2 = *(const float4*)&s_src[i][kc * 16 + 8];
            float4 s3 = *(const float4*)&s_src[i][kc * 16 + 12];
            float x;
            x = s0.x + d0.x; acc = fmaf(fabsf(x), a0.x, acc);
            x = s0.y + d0.y; acc = fmaf(fabsf(x), a0.y, acc);
            x = s0.z + d0.z; acc = fmaf(fabsf(x), a0.z, acc);
            x = s0.w + d0.w; acc = fmaf(fabsf(x), a0.w, acc);
            x = s1.x + d1.x; acc = fmaf(fabsf(x), a1.x, acc);
            x = s1.y + d1.y; acc = fmaf(fabsf(x), a1.y, acc);
            x = s1.z + d1.z; acc = fmaf(fabsf(x), a1.z, acc);
            x = s1.w + d1.w; acc = fmaf(fabsf(x), a1.w, acc);
            x = s2.x + d2.x; acc = fmaf(fabsf(x), a2.x, acc);
            x = s2.y + d2.y; acc = fmaf(fabsf(x), a2.y, acc);
            x = s2.z + d2.z; acc = fmaf(fabsf(x), a2.z, acc);
            x = s2.w + d2.w; acc = fmaf(fabsf(x), a2.w, acc);
            x = s3.x + d3.x; acc = fmaf(fabsf(x), a3.x, acc);
            x = s3.y + d3.y; acc = fmaf(fabsf(x), a3.y, acc);
            x = s3.z + d3.z; acc = fmaf(fabsf(x), a3.z, acc);
            x = s3.w + d3.w; acc = fmaf(fabsf(x), a3.w, acc);
            if (i == 0) av0 = acc; else if (i == 1) av1 = acc;
            else if (i == 2) av2 = acc; else av3 = acc;
        }
    }
    const float q6 = 0.6f * q;
    float sc[4];
    sc[0] = valid ? fmaf(0.4f, av0, q6) : -1e30f;
    sc[1] = valid ? fmaf(0.4f, av1, q6) : -1e30f;
    sc[2] = valid ? fmaf(0.4f, av2, q6) : -1e30f;
    sc[3] = valid ? fmaf(0.4f, av3, q6) : -1e30f;

    const int wave = tid >> 6, lane = tid & 63;
#pragma unroll
    for (int i = 0; i < 4; ++i) {
        float m = sc[i];
        for (int off = 1; off < 64; off <<= 1) m = fmaxf(m, __shfl_xor(m, off));
        if (lane == 0) red[wave * 4 + i] = m;
    }
    __syncthreads();
    if (tid < 4) {
        float mm = red[tid];
        for (int w = 1; w < 8; ++w) mm = fmaxf(mm, red[w * 4 + tid]);
        s_mx[tid] = mm;
    }
    __syncthreads();
    float e[4];
#pragma unroll
    for (int i = 0; i < 4; ++i) {
        e[i] = __expf(sc[i] - s_mx[i]);   // invalid j: exp(-1e30-mx) = 0
        float s = e[i];
        for (int off = 1; off < 64; off <<= 1) s += __shfl_xor(s, off);
        if (lane == 0) red[wave * 4 + i] = s;
    }
    __syncthreads();
    if (tid < 4) {
        float ss = 0.f;
        for (int w = 0; w < 8; ++w) ss += red[w * 4 + tid];
        s_rs[tid] = 1.0f / ss;
    }
    __syncthreads();
#pragma unroll
    for (int i = 0; i < 4; ++i)           // unconditional: pad j -> exact 0
        attnB[(((size_t)b * H_ + h) * NP + i0 + i) * NP + j] =
            f2bf(e[i] * s_rs[i]);
}

// ---------------------------------------------------------------------------
// FUSED msg: curr tile staged once, 4 heads looped over LDS-resident W.
// msgT[b][h][col=t*64+u][m] = bf16(0.25 * sum_d curr[b,t,m,d]*Wmsg_h[d,u])
__global__ void __launch_bounds__(256) msg_all(
    const float* __restrict__ curr, const ushort* __restrict__ WT,
    ushort* __restrict__ msgT)
{
    __shared__ ushort As[128 * 136];  // [m][d] pad+8
    __shared__ ushort Bs[64 * 136];   // [u][d] pad+8
    const int tid = threadIdx.x;
    const int m0 = blockIdx.x * 128, t = blockIdx.y, b = blockIdx.z;

    const float* cbase = curr + (size_t)(b * T_ + t) * N_ * DC;
#pragma unroll
    for (int it = 0; it < 16; ++it) {
        int e = it * 1024 + tid * 4;
        int r = e >> 7, c = e & 127;
        int gm = m0 + r;
        float4 v; v.x = v.y = v.z = v.w = 0.f;
        if (gm < N_) v = *(const float4*)&cbase[(size_t)gm * DC + c];
        ushort4 o;
        o.x = f2bf(v.x); o.y = f2bf(v.y); o.z = f2bf(v.z); o.w = f2bf(v.w);
        *(ushort4*)&As[r * 136 + c] = o;
    }

    const int wave = tid >> 6, lane = tid & 63;
    const int r15 = lane & 15, quad = lane >> 4;
    const int wm = wave >> 1, wu = wave & 1;

    for (int h = 0; h < H_; ++h) {
        __syncthreads();  // prior-iter Bs reads done (1st iter: As staged)
#pragma unroll
        for (int it = 0; it < 4; ++it) {
            int e = it * 2048 + tid * 8;
            int u = e >> 7, d = e & 127;
            *(uint4*)&Bs[u * 136 + d] =
                *(const uint4*)&WT[(size_t)h * 8192 + u * 128 + d];
        }
        __syncthreads();

        f32x4 acc[4][2] = {};
#pragma unroll
        for (int ks = 0; ks < 4; ++ks) {
            bf16x8 af[4], bg[2];
#pragma unroll
            for (int f = 0; f < 4; ++f)
                af[f] = *(const bf16x8*)&As[(wm * 64 + f * 16 + r15) * 136 + ks * 32 + quad * 8];
#pragma unroll
            for (int g = 0; g < 2; ++g)
                bg[g] = *(const bf16x8*)&Bs[(wu * 32 + g * 16 + r15) * 136 + ks * 32 + quad * 8];
#pragma unroll
            for (int f = 0; f < 4; ++f)
#pragma unroll
                for (int g = 0; g < 2; ++g)
                    acc[f][g] = __builtin_amdgcn_mfma_f32_16x16x32_bf16(af[f], bg[g], acc[f][g], 0, 0, 0);
        }
#pragma unroll
        for (int f = 0; f < 4; ++f)
#pragma unroll
            for (int g = 0; g < 2; ++g) {
                int m = m0 + wm * 64 + f * 16 + quad * 4;
                int u = wu * 32 + g * 16 + r15;
                int col = t * U_ + u;
                ushort4 o;
                o.x = f2bf(acc[f][g][0]); o.y = f2bf(acc[f][g][1]);
                o.z = f2bf(acc[f][g][2]); o.w = f2bf(acc[f][g][3]);
                *(ushort4*)&msgT[(((size_t)b * H_ + h) * COLS + col) * NP + m] = o;
            }
    }
}

// ---------------------------------------------------------------------------
// FUSED single GEMM per b: C[col=2048][i=512], K=2048 segmented over 4 heads.
// global_load_lds (16B/lane, direct-to-LDS) + XOR column swizzle
// (chunk ^= row&7) instead of +8 pad (async dest must be lane-contiguous).
__global__ void __launch_bounds__(256) gemm_big2(
    const ushort* __restrict__ msgT, const ushort* __restrict__ attnB,
    float* __restrict__ out)
{
    __shared__ ushort As[128 * 64];   // [row][chunk-swizzled 64 cols]
    __shared__ ushort Bs[128 * 64];
    const int tid = threadIdx.x;
    const int mt = blockIdx.x, nt = blockIdx.y, b = blockIdx.z;

    const int wave = tid >> 6, lane = tid & 63;
    const int r15 = lane & 15, quad = lane >> 4;
    const int wm = wave >> 1, wn = wave & 1;
    const int lrow = lane >> 3, lch = lane & 7;

    f32x4 acc[4][4] = {};
    for (int kk = 0; kk < K4; kk += 64) {
        const int hh = kk >> 9, ko = kk & (NP - 1);
        const ushort* Ab = msgT + (((size_t)b * H_ + hh) * COLS + mt * 128) * NP + ko;
        const ushort* Bb = attnB + (((size_t)b * H_ + hh) * NP + nt * 128) * NP + ko;
        // wave w stages rows [w*32, w*32+32) of both tiles: 4 loads x 8 rows
#pragma unroll
        for (int l = 0; l < 4; ++l) {
            const int R0 = wave * 32 + l * 8;          // wave-uniform
            const int row = R0 + lrow;
            const int gch = lch ^ (row & 7);
            async16(Ab + (size_t)row * NP + gch * 8, &As[R0 * 64]);
            async16(Bb + (size_t)row * NP + gch * 8, &Bs[R0 * 64]);
        }
        __syncthreads();   // compiler drains vmcnt before s_barrier
#pragma unroll
        for (int ks = 0; ks < 2; ++ks) {
            bf16x8 af[4], bg[4];
#pragma unroll
            for (int f = 0; f < 4; ++f) {
                int row = wm * 64 + f * 16 + r15;
                int c = (ks * 4 + quad) ^ (row & 7);
                af[f] = *(const bf16x8*)&As[row * 64 + c * 8];
            }
#pragma unroll
            for (int g = 0; g < 4; ++g) {
                int row = wn * 64 + g * 16 + r15;
                int c = (ks * 4 + quad) ^ (row & 7);
                bg[g] = *(const bf16x8*)&Bs[row * 64 + c * 8];
            }
#pragma unroll
            for (int f = 0; f < 4; ++f)
#pragma unroll
                for (int g = 0; g < 4; ++g)
                    acc[f][g] = __builtin_amdgcn_mfma_f32_16x16x32_bf16(af[f], bg[g], acc[f][g], 0, 0, 0);
        }
        __syncthreads();
    }

    const int t = mt * 2 + wm;
#pragma unroll
    for (int f = 0; f < 4; ++f)
#pragma unroll
        for (int g = 0; g < 4; ++g) {
            int u = f * 16 + quad * 4;
            int i = nt * 128 + wn * 64 + g * 16 + r15;
            if (i < N_) {
                float4 v;
                v.x = acc[f][g][0]; v.y = acc[f][g][1];
                v.z = acc[f][g][2]; v.w = acc[f][g][3];
                *(float4*)&out[(((size_t)b * T_ + t) * N_ + i) * U_ + u] = v;
            }
        }
}

// ---------------------------------------------------------------------------
// FALLBACK (small ws): per-head msg + gemm, same layouts.
__global__ void __launch_bounds__(256) msg_mfma(
    const float* __restrict__ curr, const ushort* __restrict__ WTh,
    ushort* __restrict__ msgT)
{
    __shared__ ushort As[128 * 136];
    __shared__ ushort Bs[64 * 136];
    const int tid = threadIdx.x;
    const int m0 = blockIdx.x * 128, t = blockIdx.y, b = blockIdx.z;

    const float* cbase = curr + (size_t)(b * T_ + t) * N_ * DC;
#pragma unroll
    for (int it = 0; it < 16; ++it) {
        int e = it * 1024 + tid * 4;
        int r = e >> 7, c = e & 127;
        int gm = m0 + r;
        float4 v; v.x = v.y = v.z = v.w = 0.f;
        if (gm < N_) v = *(const float4*)&cbase[(size_t)gm * DC + c];
        ushort4 o;
        o.x = f2bf(v.x); o.y = f2bf(v.y); o.z = f2bf(v.z); o.w = f2bf(v.w);
        *(ushort4*)&As[r * 136 + c] = o;
    }
#pragma unroll
    for (int it = 0; it < 4; ++it) {
        int e = it * 2048 + tid * 8;
        int u = e >> 7, d = e & 127;
        *(uint4*)&Bs[u * 136 + d] = *(const uint4*)&WTh[u * 128 + d];
    }
    __syncthreads();

    const int wave = tid >> 6, lane = tid & 63;
    const int r15 = lane & 15, quad = lane >> 4;
    const int wm = wave >> 1, wu = wave & 1;

    f32x4 acc[4][2] = {};
#pragma unroll
    for (int ks = 0; ks < 4; ++ks) {
        bf16x8 af[4], bg[2];
#pragma unroll
        for (int f = 0; f < 4; ++f)
            af[f] = *(const bf16x8*)&As[(wm * 64 + f * 16 + r15) * 136 + ks * 32 + quad * 8];
#pragma unroll
        for (int g = 0; g < 2; ++g)
            bg[g] = *(const bf16x8*)&Bs[(wu * 32 + g * 16 + r15) * 136 + ks * 32 + quad * 8];
#pragma unroll
        for (int f = 0; f < 4; ++f)
#pragma unroll
            for (int g = 0; g < 2; ++g)
                acc[f][g] = __builtin_amdgcn_mfma_f32_16x16x32_bf16(af[f], bg[g], acc[f][g], 0, 0, 0);
    }
#pragma unroll
    for (int f = 0; f < 4; ++f)
#pragma unroll
        for (int g = 0; g < 2; ++g) {
            int m = m0 + wm * 64 + f * 16 + quad * 4;
            int u = wu * 32 + g * 16 + r15;
            int col = t * U_ + u;
            ushort4 o;
            o.x = f2bf(acc[f][g][0]); o.y = f2bf(acc[f][g][1]);
            o.z = f2bf(acc[f][g][2]); o.w = f2bf(acc[f][g][3]);
            *(ushort4*)&msgT[((size_t)b * COLS + col) * NP + m] = o;
        }
}

__global__ void __launch_bounds__(256) gemm_mfma(
    const ushort* __restrict__ msgT, const ushort* __restrict__ attnB,
    float* __restrict__ out, int h, int init)
{
    __shared__ ushort As[64 * 72];
    __shared__ ushort Bs[64 * 72];
    const int tid = threadIdx.x;
    const int ct = blockIdx.x, it = blockIdx.y, b = blockIdx.z;

    const ushort* Ab = msgT + ((size_t)b * COLS + ct * 64) * NP;
    const ushort* Bb = attnB + (((size_t)b * H_ + h) * NP + it * 64) * NP;

    const int wave = tid >> 6, lane = tid & 63;
    const int r15 = lane & 15, quad = lane >> 4;
    const int wm = wave >> 1, wn = wave & 1;
    const int srow = tid >> 3, scol = (tid & 7) * 8;

    f32x4 acc[2][2] = {};
    for (int kk = 0; kk < NP; kk += 64) {
#pragma unroll
        for (int it2 = 0; it2 < 2; ++it2) {
            int rr = it2 * 32 + srow;
            *(uint4*)&As[rr * 72 + scol] = *(const uint4*)&Ab[(size_t)rr * NP + kk + scol];
            *(uint4*)&Bs[rr * 72 + scol] = *(const uint4*)&Bb[(size_t)rr * NP + kk + scol];
        }
        __syncthreads();
#pragma unroll
        for (int ks = 0; ks < 2; ++ks) {
            bf16x8 af[2], bg[2];
#pragma unroll
            for (int f = 0; f < 2; ++f)
                af[f] = *(const bf16x8*)&As[(wm * 32 + f * 16 + r15) * 72 + ks * 32 + quad * 8];
#pragma unroll
            for (int g = 0; g < 2; ++g)
                bg[g] = *(const bf16x8*)&Bs[(wn * 32 + g * 16 + r15) * 72 + ks * 32 + quad * 8];
#pragma unroll
            for (int f = 0; f < 2; ++f)
#pragma unroll
                for (int g = 0; g < 2; ++g)
                    acc[f][g] = __builtin_amdgcn_mfma_f32_16x16x32_bf16(af[f], bg[g], acc[f][g], 0, 0, 0);
        }
        __syncthreads();
    }

    const int t = ct;
#pragma unroll
    for (int f = 0; f < 2; ++f)
#pragma unroll
        for (int g = 0; g < 2; ++g) {
            int u = wm * 32 + f * 16 + quad * 4;
            int i = it * 64 + wn * 32 + g * 16 + r15;
            if (i < N_) {
                float* op = out + (((size_t)b * T_ + t) * N_ + i) * U_ + u;
                float4 v;
                v.x = acc[f][g][0]; v.y = acc[f][g][1];
                v.z = acc[f][g][2]; v.w = acc[f][g][3];
                if (!init) {
                    float4 old = *(const float4*)op;
                    v.x += old.x; v.y += old.y; v.z += old.z; v.w += old.w;
                }
                *(float4*)op = v;
            }
        }
}

// ---------------------------------------------------------------------------
extern "C" void kernel_launch(void* const* d_in, const int* in_sizes, int n_in,
                              void* d_out, int out_size, void* d_ws, size_t ws_size,
                              hipStream_t stream)
{
    const float* prev = (const float*)d_in[0];
    const float* curr = (const float*)d_in[1];
    const float* Wsrc = (const float*)d_in[2];
    const float* Wdst = (const float*)d_in[3];
    const float* avec = (const float*)d_in[4];
    const float* Wmsg = (const float*)d_in[5];
    float* out = (float*)d_out;

    const size_t attnB_b = (size_t)B_ * H_ * NP * NP * 2;   // 16.78 MB
    const size_t msgT4_b = (size_t)B_ * H_ * COLS * NP * 2; // 67.1 MB
    const size_t msgT1_b = (size_t)B_ * COLS * NP * 2;      // 16.78 MB
    const size_t WT_b    = (size_t)H_ * U_ * DC * 2;
    const size_t hx_b    = (size_t)B_ * H_ * N_ * U_ * 4;   // 4.1 MB

    const bool fused = ws_size >= attnB_b + msgT4_b + WT_b + 2 * hx_b;
    const size_t msg_b = fused ? msgT4_b : msgT1_b;

    ushort* attnB = (ushort*)d_ws;
    ushort* msgT  = (ushort*)((char*)d_ws + attnB_b);
    ushort* WT    = (ushort*)((char*)d_ws + attnB_b + msg_b);
    float*  hsrc  = (float*)((char*)WT + WT_b);
    float*  hdst  = (float*)((char*)hsrc + hx_b);

    prep_wT<<<128, 256, 0, stream>>>(Wmsg, WT);
    proj_all<<<1000, 512, 0, stream>>>(prev, Wsrc, Wdst, hsrc, hdst);
    // 128 i-blocks + unconditional stores: full padded tile written, no zero_fill
    attn_softmax6<<<dim3(128, B_, H_), 512, 0, stream>>>(hsrc, hdst, avec, attnB);

    if (fused) {
        msg_all<<<dim3(4, T_, B_), 256, 0, stream>>>(curr, WT, msgT);
        gemm_big2<<<dim3(16, 4, B_), 256, 0, stream>>>(msgT, attnB, out);
    } else {
        for (int h = 0; h < H_; ++h) {
            msg_mfma<<<dim3(4, T_, B_), 256, 0, stream>>>(
                curr, WT + (size_t)h * U_ * DC, msgT);
            gemm_mfma<<<dim3(32, 8, B_), 256, 0, stream>>>(
                msgT, attnB, out, h, h == 0 ? 1 : 0);
        }
    }
}

// Round 8
// 279.061 us; speedup vs baseline: 1.2017x; 1.0669x over previous
//
#include <hip/hip_runtime.h>

#define B_ 8
#define T_ 32
#define N_ 500
#define DP 200
#define DC 128
#define H_ 4
#define U_ 64
#define NP 512           // padded N
#define COLS (T_ * U_)   // 2048
#define K4 (H_ * NP)     // 2048 fused K

typedef __attribute__((ext_vector_type(8))) short bf16x8;
typedef __attribute__((ext_vector_type(4))) float f32x4;

typedef const __attribute__((address_space(1))) void* gcptr_t;
typedef __attribute__((address_space(3))) void* lptr_t;

// async 16B/lane global->LDS; lds base must be wave-uniform (dest = base + lane*16)
__device__ __forceinline__ void async16(const void* g, void* lds) {
    __builtin_amdgcn_global_load_lds((gcptr_t)g, (lptr_t)lds, 16, 0, 0);
}

__device__ __forceinline__ ushort f2bf(float f) {
    unsigned u = __float_as_uint(f);
    unsigned r = (u + 0x7FFFu + ((u >> 16) & 1u)) >> 16;  // RTNE
    return (ushort)r;
}

// ---------------------------------------------------------------------------
// WT[h][u][d] = bf16(0.25 * Wmsg[h][d][u])  (0.25 = head mean, exact pow2)
__global__ void prep_wT(const float* __restrict__ Wmsg, ushort* __restrict__ WT) {
    int idx = blockIdx.x * 256 + threadIdx.x;
    int h = idx >> 13, u = (idx >> 7) & 63, d = idx & 127;
    WT[idx] = f2bf(0.25f * Wmsg[((size_t)h * DC + d) * U_ + u]);
}

// ---------------------------------------------------------------------------
// Projections for ALL heads, 4 node-rows per block. hsrc/hdst [B,H,N,U] fp32.
__global__ void __launch_bounds__(512) proj_all(
    const float* __restrict__ prev, const float* __restrict__ Wsrc,
    const float* __restrict__ Wdst, float* __restrict__ hsrc,
    float* __restrict__ hdst)
{
    __shared__ float rows[4 * DP];
    const int tid = threadIdx.x;
    const int bn0 = blockIdx.x * 4;
    for (int e = tid; e < 4 * DP; e += 512) rows[e] = prev[(size_t)bn0 * DP + e];
    __syncthreads();
    const int u = tid & 63;
    const int h = (tid >> 6) & 3;
    const int isdst = tid >> 8;
    const float* W = (isdst ? Wdst : Wsrc) + (size_t)h * DP * U_;
    float a0 = 0.f, a1 = 0.f, a2 = 0.f, a3 = 0.f;
#pragma unroll 4
    for (int d = 0; d < DP; ++d) {
        float w = W[d * U_ + u];
        a0 = fmaf(rows[d], w, a0);
        a1 = fmaf(rows[DP + d], w, a1);
        a2 = fmaf(rows[2 * DP + d], w, a2);
        a3 = fmaf(rows[3 * DP + d], w, a3);
    }
    float acc[4] = {a0, a1, a2, a3};
    float* o = isdst ? hdst : hsrc;
#pragma unroll
    for (int r = 0; r < 4; ++r) {
        int bn = bn0 + r, b = bn / N_, n = bn - b * N_;
        o[(((size_t)b * H_ + h) * N_ + n) * U_ + u] = acc[r];
    }
}

// ---------------------------------------------------------------------------
// Scores + softmax. lrelu(x)=0.6x+0.4|x|; row-constant 0.6*P_i cancels ->
// score' = 0.6*Q_j + 0.4*sum_u a_u*|s_iu+d_ju|.
// R8: s_src / a are BLOCK-UNIFORM -> read straight from global with uniform
// addresses (LLVM scalarizes to s_load; SMEM runs parallel to VALU) instead
// of LDS staging + 80 ds_read_b128/wave (the R7 LDS-throughput floor).
// Row index clamped to N_-1 so pad i rows read in-bounds (finite garbage,
// consumed only by masked output rows); pad j cols still exact 0.
// Chunk loop stays `#pragma unroll 1` (R5 lesson: hoisting -> spill).
__global__ void __launch_bounds__(512) attn_softmax7(
    const float* __restrict__ hsrc, const float* __restrict__ hdst,
    const float* __restrict__ a_all, ushort* __restrict__ attnB)
{
    const int i0 = blockIdx.x * 4, b = blockIdx.y, h = blockIdx.z;
    const int tid = threadIdx.x;
    __shared__ float red[32];     // [wave][i]
    __shared__ float s_mx[4], s_rs[4];

    const float* ap = a_all + (size_t)h * U_;
    const float* hb = hsrc + (((size_t)b * H_ + h) * N_) * U_;
    const float* sr0 = hb + (size_t)min(i0 + 0, N_ - 1) * U_;  // uniform rows
    const float* sr1 = hb + (size_t)min(i0 + 1, N_ - 1) * U_;
    const float* sr2 = hb + (size_t)min(i0 + 2, N_ - 1) * U_;
    const float* sr3 = hb + (size_t)min(i0 + 3, N_ - 1) * U_;

    const int j = tid;
    const bool valid = j < N_;
    const float4* dp =
        (const float4*)&hdst[(((size_t)b * H_ + h) * N_ + (valid ? j : 0)) * U_];

    float av0 = 0.f, av1 = 0.f, av2 = 0.f, av3 = 0.f;
    float q = 0.f;
#pragma unroll 1
    for (int kc = 0; kc < 4; ++kc) {         // SEQUENTIAL: 4 chunks of 16
        const int o = kc * 16;
        float dv[16];
        *(float4*)&dv[0]  = dp[kc * 4 + 0];
        *(float4*)&dv[4]  = dp[kc * 4 + 1];
        *(float4*)&dv[8]  = dp[kc * 4 + 2];
        *(float4*)&dv[12] = dp[kc * 4 + 3];
#pragma unroll
        for (int u = 0; u < 16; ++u) {
            const float au = ap[o + u];       // uniform -> SGPR
            const float du = dv[u];           // per-lane VGPR
            q   = fmaf(du, au, q);
            av0 = fmaf(fabsf(sr0[o + u] + du), au, av0);
            av1 = fmaf(fabsf(sr1[o + u] + du), au, av1);
            av2 = fmaf(fabsf(sr2[o + u] + du), au, av2);
            av3 = fmaf(fabsf(sr3[o + u] + du), au, av3);
        }
    }
    const float q6 = 0.6f * q;
    float sc[4];
    sc[0] = valid ? fmaf(0.4f, av0, q6) : -1e30f;
    sc[1] = valid ? fmaf(0.4f, av1, q6) : -1e30f;
    sc[2] = valid ? fmaf(0.4f, av2, q6) : -1e30f;
    sc[3] = valid ? fmaf(0.4f, av3, q6) : -1e30f;

    const int wave = tid >> 6, lane = tid & 63;
#pragma unroll
    for (int i = 0; i < 4; ++i) {
        float m = sc[i];
        for (int off = 1; off < 64; off <<= 1) m = fmaxf(m, __shfl_xor(m, off));
        if (lane == 0) red[wave * 4 + i] = m;
    }
    __syncthreads();
    if (tid < 4) {
        float mm = red[tid];
        for (int w = 1; w < 8; ++w) mm = fmaxf(mm, red[w * 4 + tid]);
        s_mx[tid] = mm;
    }
    __syncthreads();
    float e[4];
#pragma unroll
    for (int i = 0; i < 4; ++i) {
        e[i] = __expf(sc[i] - s_mx[i]);   // invalid j: exp(-1e30-mx) = 0
        float s = e[i];
        for (int off = 1; off < 64; off <<= 1) s += __shfl_xor(s, off);
        if (lane == 0) red[wave * 4 + i] = s;
    }
    __syncthreads();
    if (tid < 4) {
        float ss = 0.f;
        for (int w = 0; w < 8; ++w) ss += red[w * 4 + tid];
        s_rs[tid] = 1.0f / ss;
    }
    __syncthreads();
#pragma unroll
    for (int i = 0; i < 4; ++i)           // unconditional: pad j -> exact 0
        attnB[(((size_t)b * H_ + h) * NP + i0 + i) * NP + j] =
            f2bf(e[i] * s_rs[i]);
}

// ---------------------------------------------------------------------------
// FUSED msg: curr tile staged once, 4 heads looped over LDS-resident W.
// msgT[b][h][col=t*64+u][m] = bf16(0.25 * sum_d curr[b,t,m,d]*Wmsg_h[d,u])
__global__ void __launch_bounds__(256) msg_all(
    const float* __restrict__ curr, const ushort* __restrict__ WT,
    ushort* __restrict__ msgT)
{
    __shared__ ushort As[128 * 136];  // [m][d] pad+8
    __shared__ ushort Bs[64 * 136];   // [u][d] pad+8
    const int tid = threadIdx.x;
    const int m0 = blockIdx.x * 128, t = blockIdx.y, b = blockIdx.z;

    const float* cbase = curr + (size_t)(b * T_ + t) * N_ * DC;
#pragma unroll
    for (int it = 0; it < 16; ++it) {
        int e = it * 1024 + tid * 4;
        int r = e >> 7, c = e & 127;
        int gm = m0 + r;
        float4 v; v.x = v.y = v.z = v.w = 0.f;
        if (gm < N_) v = *(const float4*)&cbase[(size_t)gm * DC + c];
        ushort4 o;
        o.x = f2bf(v.x); o.y = f2bf(v.y); o.z = f2bf(v.z); o.w = f2bf(v.w);
        *(ushort4*)&As[r * 136 + c] = o;
    }

    const int wave = tid >> 6, lane = tid & 63;
    const int r15 = lane & 15, quad = lane >> 4;
    const int wm = wave >> 1, wu = wave & 1;

    for (int h = 0; h < H_; ++h) {
        __syncthreads();  // prior-iter Bs reads done (1st iter: As staged)
#pragma unroll
        for (int it = 0; it < 4; ++it) {
            int e = it * 2048 + tid * 8;
            int u = e >> 7, d = e & 127;
            *(uint4*)&Bs[u * 136 + d] =
                *(const uint4*)&WT[(size_t)h * 8192 + u * 128 + d];
        }
        __syncthreads();

        f32x4 acc[4][2] = {};
#pragma unroll
        for (int ks = 0; ks < 4; ++ks) {
            bf16x8 af[4], bg[2];
#pragma unroll
            for (int f = 0; f < 4; ++f)
                af[f] = *(const bf16x8*)&As[(wm * 64 + f * 16 + r15) * 136 + ks * 32 + quad * 8];
#pragma unroll
            for (int g = 0; g < 2; ++g)
                bg[g] = *(const bf16x8*)&Bs[(wu * 32 + g * 16 + r15) * 136 + ks * 32 + quad * 8];
#pragma unroll
            for (int f = 0; f < 4; ++f)
#pragma unroll
                for (int g = 0; g < 2; ++g)
                    acc[f][g] = __builtin_amdgcn_mfma_f32_16x16x32_bf16(af[f], bg[g], acc[f][g], 0, 0, 0);
        }
#pragma unroll
        for (int f = 0; f < 4; ++f)
#pragma unroll
            for (int g = 0; g < 2; ++g) {
                int m = m0 + wm * 64 + f * 16 + quad * 4;
                int u = wu * 32 + g * 16 + r15;
                int col = t * U_ + u;
                ushort4 o;
                o.x = f2bf(acc[f][g][0]); o.y = f2bf(acc[f][g][1]);
                o.z = f2bf(acc[f][g][2]); o.w = f2bf(acc[f][g][3]);
                *(ushort4*)&msgT[(((size_t)b * H_ + h) * COLS + col) * NP + m] = o;
            }
    }
}

// ---------------------------------------------------------------------------
// FUSED single GEMM per b: C[col=2048][i=512], K=2048 segmented over 4 heads.
// global_load_lds (16B/lane, direct-to-LDS) + XOR column swizzle
// (chunk ^= row&7) instead of +8 pad (async dest must be lane-contiguous).
__global__ void __launch_bounds__(256) gemm_big2(
    const ushort* __restrict__ msgT, const ushort* __restrict__ attnB,
    float* __restrict__ out)
{
    __shared__ ushort As[128 * 64];   // [row][chunk-swizzled 64 cols]
    __shared__ ushort Bs[128 * 64];
    const int tid = threadIdx.x;
    const int mt = blockIdx.x, nt = blockIdx.y, b = blockIdx.z;

    const int wave = tid >> 6, lane = tid & 63;
    const int r15 = lane & 15, quad = lane >> 4;
    const int wm = wave >> 1, wn = wave & 1;
    const int lrow = lane >> 3, lch = lane & 7;

    f32x4 acc[4][4] = {};
    for (int kk = 0; kk < K4; kk += 64) {
        const int hh = kk >> 9, ko = kk & (NP - 1);
        const ushort* Ab = msgT + (((size_t)b * H_ + hh) * COLS + mt * 128) * NP + ko;
        const ushort* Bb = attnB + (((size_t)b * H_ + hh) * NP + nt * 128) * NP + ko;
        // wave w stages rows [w*32, w*32+32) of both tiles: 4 loads x 8 rows
#pragma unroll
        for (int l = 0; l < 4; ++l) {
            const int R0 = wave * 32 + l * 8;          // wave-uniform
            const int row = R0 + lrow;
            const int gch = lch ^ (row & 7);
            async16(Ab + (size_t)row * NP + gch * 8, &As[R0 * 64]);
            async16(Bb + (size_t)row * NP + gch * 8, &Bs[R0 * 64]);
        }
        __syncthreads();   // compiler drains vmcnt before s_barrier
#pragma unroll
        for (int ks = 0; ks < 2; ++ks) {
            bf16x8 af[4], bg[4];
#pragma unroll
            for (int f = 0; f < 4; ++f) {
                int row = wm * 64 + f * 16 + r15;
                int c = (ks * 4 + quad) ^ (row & 7);
                af[f] = *(const bf16x8*)&As[row * 64 + c * 8];
            }
#pragma unroll
            for (int g = 0; g < 4; ++g) {
                int row = wn * 64 + g * 16 + r15;
                int c = (ks * 4 + quad) ^ (row & 7);
                bg[g] = *(const bf16x8*)&Bs[row * 64 + c * 8];
            }
#pragma unroll
            for (int f = 0; f < 4; ++f)
#pragma unroll
                for (int g = 0; g < 4; ++g)
                    acc[f][g] = __builtin_amdgcn_mfma_f32_16x16x32_bf16(af[f], bg[g], acc[f][g], 0, 0, 0);
        }
        __syncthreads();
    }

    const int t = mt * 2 + wm;
#pragma unroll
    for (int f = 0; f < 4; ++f)
#pragma unroll
        for (int g = 0; g < 4; ++g) {
            int u = f * 16 + quad * 4;
            int i = nt * 128 + wn * 64 + g * 16 + r15;
            if (i < N_) {
                float4 v;
                v.x = acc[f][g][0]; v.y = acc[f][g][1];
                v.z = acc[f][g][2]; v.w = acc[f][g][3];
                *(float4*)&out[(((size_t)b * T_ + t) * N_ + i) * U_ + u] = v;
            }
        }
}

// ---------------------------------------------------------------------------
// FALLBACK (small ws): per-head msg + gemm, same layouts.
__global__ void __launch_bounds__(256) msg_mfma(
    const float* __restrict__ curr, const ushort* __restrict__ WTh,
    ushort* __restrict__ msgT)
{
    __shared__ ushort As[128 * 136];
    __shared__ ushort Bs[64 * 136];
    const int tid = threadIdx.x;
    const int m0 = blockIdx.x * 128, t = blockIdx.y, b = blockIdx.z;

    const float* cbase = curr + (size_t)(b * T_ + t) * N_ * DC;
#pragma unroll
    for (int it = 0; it < 16; ++it) {
        int e = it * 1024 + tid * 4;
        int r = e >> 7, c = e & 127;
        int gm = m0 + r;
        float4 v; v.x = v.y = v.z = v.w = 0.f;
        if (gm < N_) v = *(const float4*)&cbase[(size_t)gm * DC + c];
        ushort4 o;
        o.x = f2bf(v.x); o.y = f2bf(v.y); o.z = f2bf(v.z); o.w = f2bf(v.w);
        *(ushort4*)&As[r * 136 + c] = o;
    }
#pragma unroll
    for (int it = 0; it < 4; ++it) {
        int e = it * 2048 + tid * 8;
        int u = e >> 7, d = e & 127;
        *(uint4*)&Bs[u * 136 + d] = *(const uint4*)&WTh[u * 128 + d];
    }
    __syncthreads();

    const int wave = tid >> 6, lane = tid & 63;
    const int r15 = lane & 15, quad = lane >> 4;
    const int wm = wave >> 1, wu = wave & 1;

    f32x4 acc[4][2] = {};
#pragma unroll
    for (int ks = 0; ks < 4; ++ks) {
        bf16x8 af[4], bg[2];
#pragma unroll
        for (int f = 0; f < 4; ++f)
            af[f] = *(const bf16x8*)&As[(wm * 64 + f * 16 + r15) * 136 + ks * 32 + quad * 8];
#pragma unroll
        for (int g = 0; g < 2; ++g)
            bg[g] = *(const bf16x8*)&Bs[(wu * 32 + g * 16 + r15) * 136 + ks * 32 + quad * 8];
#pragma unroll
        for (int f = 0; f < 4; ++f)
#pragma unroll
            for (int g = 0; g < 2; ++g)
                acc[f][g] = __builtin_amdgcn_mfma_f32_16x16x32_bf16(af[f], bg[g], acc[f][g], 0, 0, 0);
    }
#pragma unroll
    for (int f = 0; f < 4; ++f)
#pragma unroll
        for (int g = 0; g < 2; ++g) {
            int m = m0 + wm * 64 + f * 16 + quad * 4;
            int u = wu * 32 + g * 16 + r15;
            int col = t * U_ + u;
            ushort4 o;
            o.x = f2bf(acc[f][g][0]); o.y = f2bf(acc[f][g][1]);
            o.z = f2bf(acc[f][g][2]); o.w = f2bf(acc[f][g][3]);
            *(ushort4*)&msgT[((size_t)b * COLS + col) * NP + m] = o;
        }
}

__global__ void __launch_bounds__(256) gemm_mfma(
    const ushort* __restrict__ msgT, const ushort* __restrict__ attnB,
    float* __restrict__ out, int h, int init)
{
    __shared__ ushort As[64 * 72];
    __shared__ ushort Bs[64 * 72];
    const int tid = threadIdx.x;
    const int ct = blockIdx.x, it = blockIdx.y, b = blockIdx.z;

    const ushort* Ab = msgT + ((size_t)b * COLS + ct * 64) * NP;
    const ushort* Bb = attnB + (((size_t)b * H_ + h) * NP + it * 64) * NP;

    const int wave = tid >> 6, lane = tid & 63;
    const int r15 = lane & 15, quad = lane >> 4;
    const int wm = wave >> 1, wn = wave & 1;
    const int srow = tid >> 3, scol = (tid & 7) * 8;

    f32x4 acc[2][2] = {};
    for (int kk = 0; kk < NP; kk += 64) {
#pragma unroll
        for (int it2 = 0; it2 < 2; ++it2) {
            int rr = it2 * 32 + srow;
            *(uint4*)&As[rr * 72 + scol] = *(const uint4*)&Ab[(size_t)rr * NP + kk + scol];
            *(uint4*)&Bs[rr * 72 + scol] = *(const uint4*)&Bb[(size_t)rr * NP + kk + scol];
        }
        __syncthreads();
#pragma unroll
        for (int ks = 0; ks < 2; ++ks) {
            bf16x8 af[2], bg[2];
#pragma unroll
            for (int f = 0; f < 2; ++f)
                af[f] = *(const bf16x8*)&As[(wm * 32 + f * 16 + r15) * 72 + ks * 32 + quad * 8];
#pragma unroll
            for (int g = 0; g < 2; ++g)
                bg[g] = *(const bf16x8*)&Bs[(wn * 32 + g * 16 + r15) * 72 + ks * 32 + quad * 8];
#pragma unroll
            for (int f = 0; f < 2; ++f)
#pragma unroll
                for (int g = 0; g < 2; ++g)
                    acc[f][g] = __builtin_amdgcn_mfma_f32_16x16x32_bf16(af[f], bg[g], acc[f][g], 0, 0, 0);
        }
        __syncthreads();
    }

    const int t = ct;
#pragma unroll
    for (int f = 0; f < 2; ++f)
#pragma unroll
        for (int g = 0; g < 2; ++g) {
            int u = wm * 32 + f * 16 + quad * 4;
            int i = it * 64 + wn * 32 + g * 16 + r15;
            if (i < N_) {
                float* op = out + (((size_t)b * T_ + t) * N_ + i) * U_ + u;
                float4 v;
                v.x = acc[f][g][0]; v.y = acc[f][g][1];
                v.z = acc[f][g][2]; v.w = acc[f][g][3];
                if (!init) {
                    float4 old = *(const float4*)op;
                    v.x += old.x; v.y += old.y; v.z += old.z; v.w += old.w;
                }
                *(float4*)op = v;
            }
        }
}

// ---------------------------------------------------------------------------
extern "C" void kernel_launch(void* const* d_in, const int* in_sizes, int n_in,
                              void* d_out, int out_size, void* d_ws, size_t ws_size,
                              hipStream_t stream)
{
    const float* prev = (const float*)d_in[0];
    const float* curr = (const float*)d_in[1];
    const float* Wsrc = (const float*)d_in[2];
    const float* Wdst = (const float*)d_in[3];
    const float* avec = (const float*)d_in[4];
    const float* Wmsg = (const float*)d_in[5];
    float* out = (float*)d_out;

    const size_t attnB_b = (size_t)B_ * H_ * NP * NP * 2;   // 16.78 MB
    const size_t msgT4_b = (size_t)B_ * H_ * COLS * NP * 2; // 67.1 MB
    const size_t msgT1_b = (size_t)B_ * COLS * NP * 2;      // 16.78 MB
    const size_t WT_b    = (size_t)H_ * U_ * DC * 2;
    const size_t hx_b    = (size_t)B_ * H_ * N_ * U_ * 4;   // 4.1 MB

    const bool fused = ws_size >= attnB_b + msgT4_b + WT_b + 2 * hx_b;
    const size_t msg_b = fused ? msgT4_b : msgT1_b;

    ushort* attnB = (ushort*)d_ws;
    ushort* msgT  = (ushort*)((char*)d_ws + attnB_b);
    ushort* WT    = (ushort*)((char*)d_ws + attnB_b + msg_b);
    float*  hsrc  = (float*)((char*)WT + WT_b);
    float*  hdst  = (float*)((char*)hsrc + hx_b);

    prep_wT<<<128, 256, 0, stream>>>(Wmsg, WT);
    proj_all<<<1000, 512, 0, stream>>>(prev, Wsrc, Wdst, hsrc, hdst);
    // 128 i-blocks + unconditional stores: full padded tile written, no zero_fill
    attn_softmax7<<<dim3(128, B_, H_), 512, 0, stream>>>(hsrc, hdst, avec, attnB);

    if (fused) {
        msg_all<<<dim3(4, T_, B_), 256, 0, stream>>>(curr, WT, msgT);
        gemm_big2<<<dim3(16, 4, B_), 256, 0, stream>>>(msgT, attnB, out);
    } else {
        for (int h = 0; h < H_; ++h) {
            msg_mfma<<<dim3(4, T_, B_), 256, 0, stream>>>(
                curr, WT + (size_t)h * U_ * DC, msgT);
            gemm_mfma<<<dim3(32, 8, B_), 256, 0, stream>>>(
                msgT, attnB, out, h, h == 0 ? 1 : 0);
        }
    }
}